// Round 8
// baseline (182.349 us; speedup 1.0000x reference)
//
#include <hip/hip_runtime.h>
#include <math.h>

#define NPTS 131072
#define KCOMP 256
#define DIM 32
#define NREAL 560                 // 528 tight-packed quad + 32 linear
#define NCH 18                    // 32-feature chunks: 17 full + 1 half (16)
#define PSIF_BYTES 294912         // 18 chunks * 1024 granules * 16 B
#define WS_NEED (PSIF_BYTES + KCOMP * 4)

typedef __attribute__((ext_vector_type(8))) short short8;
typedef __attribute__((ext_vector_type(16))) float f32x16;

__device__ __forceinline__ unsigned short f2bf(float v) {
    unsigned u = __float_as_uint(v);
    u += 0x7fffu + ((u >> 16) & 1u);   // RNE
    return (unsigned short)(u >> 16);
}

// pack two f32 -> two bf16 (lo | hi<<16). RTN (+0x8000) + byte-perm: 3 ops.
__device__ __forceinline__ unsigned pkbf(float lo, float hi) {
#if __has_builtin(__builtin_amdgcn_perm)
    const unsigned a = __float_as_uint(hi) + 0x8000u;
    const unsigned b = __float_as_uint(lo) + 0x8000u;
    return __builtin_amdgcn_perm(a, b, 0x07060302u);
#else
    return (unsigned)f2bf(lo) | ((unsigned)f2bf(hi) << 16);
#endif
}

// ---- compile-time feature decode: TIGHT triangular packing ----------------
// p in [0,528): (d,f) pairs, f>=d, row-major (row d has 32-d entries).
// p in [528,560): linear features (index p-528).
constexpr int PfxT(int d) { return 32 * d - (d * (d - 1)) / 2; }
constexpr int rowT(int p) { int d = 0; while (d < 31 && PfxT(d + 1) <= p) ++d; return d; }
constexpr int colT(int p) { return rowT(p) + (p - PfxT(rowT(p))); }

template<int P, int J>
__device__ __forceinline__ float genOne(const float (&x)[DIM]) {
    constexpr int p = P + J;
    if constexpr (p >= NREAL) {
        return 0.f;
    } else if constexpr (p >= 528) {
        return x[p - 528];
    } else {
        constexpr int d = rowT(p);
        constexpr int f = colT(p);
        static_assert(d >= 0 && d < 32 && f >= d && f < 32, "bad feature map");
        return x[d] * x[f];
    }
}

// ---------------------------------------------------------------------------
// Precompute: Psi column k scattered into frag-ordered PsiF (bf16), kc2 fp32.
// ---------------------------------------------------------------------------
__global__ __launch_bounds__(256) void gmm_pre(
    const float* __restrict__ S,
    const float* __restrict__ centers,
    const float* __restrict__ weights,
    unsigned short* __restrict__ PsiF,
    float* __restrict__ kc2)
{
    __shared__ float Sl[DIM][DIM + 1];
    __shared__ float As[DIM][DIM + 1];
    __shared__ float cl[DIM], ml[DIM];
    __shared__ float red[256];

    const int k = blockIdx.x, tid = threadIdx.x;

    for (int idx = tid; idx < DIM * DIM; idx += 256)
        Sl[idx >> 5][idx & 31] = S[(size_t)k * DIM * DIM + idx];
    if (tid < DIM) cl[tid] = centers[k * DIM + tid];
    __syncthreads();

    // A = S S^T
    for (int idx = tid; idx < DIM * DIM; idx += 256) {
        const int d = idx >> 5, f = idx & 31;
        float a = 0.f;
#pragma unroll
        for (int e = 0; e < DIM; ++e) a = fmaf(Sl[d][e], Sl[f][e], a);
        As[d][f] = a;
    }
    __syncthreads();

    if (tid < DIM) {
        float mv = 0.f;
#pragma unroll
        for (int f = 0; f < DIM; ++f) mv = fmaf(As[tid][f], cl[f], mv);
        ml[tid] = mv;
    }
    __syncthreads();

    // scatter Psi column k into frag positions (reads As diag+upper, ml).
    for (int p = tid; p < NREAL; p += 256) {
        float val;
        if (p < 528) {
            int d = 0, pr = 0;
            while (pr + (32 - d) <= p) { pr += (32 - d); ++d; }
            const int f = d + (p - pr);
            val = (f == d) ? -0.5f * As[d][d] : -As[d][f];
        } else {
            val = ml[p - 528];
        }
        const int c = p >> 6, kk = p & 63;
        const int s = kk >> 4, qq = (kk >> 3) & 1, j = kk & 7;
        const int ct = k >> 5, ll = qq * 32 + (k & 31);
        const int g = c * 2048 + (s * 8 + ct) * 64 + ll;
        PsiF[(size_t)g * 8 + j] = f2bf(val);
    }

    red[tid] = fabsf(weights[tid]);          // K == 256 == blockDim
    __syncthreads();                          // also fences As/ml reads above
    for (int off = 128; off > 0; off >>= 1) {
        if (tid < off) red[tid] += red[tid + off];
        __syncthreads();
    }
    const float wsum = red[0];

    // SPD Gaussian elimination: 1 barrier/step, logdet(A) = sum log(pivot_j).
    for (int j = 0; j < DIM - 1; ++j) {
        const float inv = 1.0f / As[j][j];
        for (int idx = tid; idx < DIM * DIM; idx += 256) {
            const int r = idx >> 5, c = idx & 31;
            if (r > j && c > j)
                As[r][c] = fmaf(-As[r][j] * inv, As[j][c], As[r][c]);
        }
        __syncthreads();
    }

    if (tid < DIM) red[tid] = __logf(As[tid][tid]);   // pivots > 0 (SPD)
    __syncthreads();
    if (tid == 0) {
        float sl = 0.f;
        for (int j = 0; j < DIM; ++j) sl += red[j];
        float cac = 0.f;
        for (int d2 = 0; d2 < DIM; ++d2) cac = fmaf(ml[d2], cl[d2], cac);
        kc2[k] = __logf(fabsf(weights[k])) - __logf(wsum + 1e-30f)
               + 0.5f * sl - 0.5f * cac;
    }
}

// ---------------------------------------------------------------------------
// Main MFMA kernel v9: BARRIER-FREE, LDS-FREE main loop.
// 256 threads (4 waves) per 32-row block; wave = 32r x 64c (cq = wave id),
// acc = 2 x f32x16 = 32 AGPR. A-fragments genned in registers per lane
// (v5-verified mapping: lane l supplies features C*32+S*16+(l>>5)*8+{0..7}
// of row l&31; both k-groups computed, cndmask-selected -- 2x gen cost,
// zero LDS, zero barriers). B read straight from L2 (PsiF is 288 KB,
// L2-resident) as coalesced dwordx4, double-buffered in registers 1 chunk
// ahead; the compiler's own vmcnt waits cover the L2 latency with a full
// chunk body (gen ~170 cy + 4 MFMA). No __syncthreads until the 1-KB
// epilogue. __launch_bounds__(256,3): ~170-reg cap so NOTHING spills
// (R7 lesson: a reg cap below live state = 46 MB scratch traffic).
// ---------------------------------------------------------------------------
template<int P>
__device__ __forceinline__ uint4 packFrag8(const float (&x)[DIM]) {
    const float v0 = genOne<P, 0>(x), v1 = genOne<P, 1>(x);
    const float v2 = genOne<P, 2>(x), v3 = genOne<P, 3>(x);
    const float v4 = genOne<P, 4>(x), v5 = genOne<P, 5>(x);
    const float v6 = genOne<P, 6>(x), v7 = genOne<P, 7>(x);
    uint4 u;
    u.x = pkbf(v0, v1);
    u.y = pkbf(v2, v3);
    u.z = pkbf(v4, v5);
    u.w = pkbf(v6, v7);
    return u;
}

// A-fragment for K16-step S of chunk C (verified correct in R5's kernel)
template<int C, int S>
__device__ __forceinline__ short8 aFrag(const float (&x)[DIM], bool kgb) {
    const uint4 f0 = packFrag8<C * 32 + S * 16 + 0>(x);   // k-group 0
    const uint4 f1 = packFrag8<C * 32 + S * 16 + 8>(x);   // k-group 1
    uint4 fs;
    fs.x = kgb ? f1.x : f0.x;
    fs.y = kgb ? f1.y : f0.y;
    fs.z = kgb ? f1.z : f0.z;
    fs.w = kgb ? f1.w : f0.w;
    return __builtin_bit_cast(short8, fs);
}

// B granules for chunk C, this wave's two 32-col groups (ct = cq*2 + j):
// granule index = C*1024 + (S*8 + ct)*64 + l  (identical bytes the LDS
// version read; now straight from global/L2, perfectly lane-coalesced).
template<int C>
__device__ __forceinline__ void loadB(const uint4* __restrict__ PsiF4,
                                      uint4 (&st)[4], int l, int cq) {
    const uint4* p = PsiF4 + C * 1024 + (cq * 2) * 64 + l;
    st[0] = p[0];                    // S0, j0
    st[1] = p[64];                   // S0, j1
    if constexpr (C < 17) {
        st[2] = p[512];              // S1, j0
        st[3] = p[512 + 64];         // S1, j1
    }
}

template<int C>
__device__ __forceinline__ void doChunk(const float (&x)[DIM],
    const uint4* __restrict__ PsiF4,
    uint4 (&cur)[4], uint4 (&nxt)[4],
    f32x16 (&acc)[2], int l, int cq, bool kgb)
{
    // prefetch next chunk's B into the other stage (in flight across this
    // body; compiler inserts the vmcnt before first use next chunk)
    if constexpr (C + 1 < NCH) loadB<C + 1>(PsiF4, nxt, l, cq);

    const short8 a0 = aFrag<C, 0>(x, kgb);
    acc[0] = __builtin_amdgcn_mfma_f32_32x32x16_bf16(
        a0, __builtin_bit_cast(short8, cur[0]), acc[0], 0, 0, 0);
    acc[1] = __builtin_amdgcn_mfma_f32_32x32x16_bf16(
        a0, __builtin_bit_cast(short8, cur[1]), acc[1], 0, 0, 0);

    if constexpr (C < 17) {
        const short8 a1 = aFrag<C, 1>(x, kgb);
        acc[0] = __builtin_amdgcn_mfma_f32_32x32x16_bf16(
            a1, __builtin_bit_cast(short8, cur[2]), acc[0], 0, 0, 0);
        acc[1] = __builtin_amdgcn_mfma_f32_32x32x16_bf16(
            a1, __builtin_bit_cast(short8, cur[3]), acc[1], 0, 0, 0);
    }
}

__global__ __launch_bounds__(256, 3) void gmm_mfma(
    const float* __restrict__ points,
    const unsigned short* __restrict__ PsiF,
    const float* __restrict__ kc2,
    const float* __restrict__ thr,
    float* __restrict__ out)
{
    __shared__ float sM[32][4];          // 512 B epilogue scratch
    __shared__ float sS[32][4];          // 512 B

    const int t = threadIdx.x;
    const int cq = t >> 6, l = t & 63;   // wave cq covers cols cq*64..+64
    const bool kgb = (l >= 32);
    const int r32 = l & 31;              // the row this lane feeds

    const uint4* PsiF4 = (const uint4*)PsiF;

    // x of this lane's row (lanes l and l+32 duplicate; cache-served)
    float x[DIM];
    const float4* px = (const float4*)(points + ((size_t)blockIdx.x * 32 + r32) * DIM);
#pragma unroll
    for (int j2 = 0; j2 < 8; ++j2) {
        float4 v = px[j2];
        x[4 * j2 + 0] = v.x; x[4 * j2 + 1] = v.y;
        x[4 * j2 + 2] = v.z; x[4 * j2 + 3] = v.w;
    }

    f32x16 acc[2];
#pragma unroll
    for (int j = 0; j < 2; ++j)
#pragma unroll
        for (int r = 0; r < 16; ++r) acc[j][r] = 0.f;

    uint4 stA[4], stB[4];
    loadB<0>(PsiF4, stA, l, cq);

    doChunk<0>(x, PsiF4, stA, stB, acc, l, cq, kgb);
    doChunk<1>(x, PsiF4, stB, stA, acc, l, cq, kgb);
    doChunk<2>(x, PsiF4, stA, stB, acc, l, cq, kgb);
    doChunk<3>(x, PsiF4, stB, stA, acc, l, cq, kgb);
    doChunk<4>(x, PsiF4, stA, stB, acc, l, cq, kgb);
    doChunk<5>(x, PsiF4, stB, stA, acc, l, cq, kgb);
    doChunk<6>(x, PsiF4, stA, stB, acc, l, cq, kgb);
    doChunk<7>(x, PsiF4, stB, stA, acc, l, cq, kgb);
    doChunk<8>(x, PsiF4, stA, stB, acc, l, cq, kgb);
    doChunk<9>(x, PsiF4, stB, stA, acc, l, cq, kgb);
    doChunk<10>(x, PsiF4, stA, stB, acc, l, cq, kgb);
    doChunk<11>(x, PsiF4, stB, stA, acc, l, cq, kgb);
    doChunk<12>(x, PsiF4, stA, stB, acc, l, cq, kgb);
    doChunk<13>(x, PsiF4, stB, stA, acc, l, cq, kgb);
    doChunk<14>(x, PsiF4, stA, stB, acc, l, cq, kgb);
    doChunk<15>(x, PsiF4, stB, stA, acc, l, cq, kgb);
    doChunk<16>(x, PsiF4, stA, stB, acc, l, cq, kgb);
    doChunk<17>(x, PsiF4, stB, stA, acc, l, cq, kgb);

    // epilogue: add kc2, row-wise LSE over this wave's 64 cols, then 4-way
    // merge across waves via 1 KB LDS (the kernel's only barrier).
    const float kcv0 = kc2[(cq * 2 + 0) * 32 + r32];
    const float kcv1 = kc2[(cq * 2 + 1) * 32 + r32];

#pragma unroll
    for (int rg = 0; rg < 16; ++rg) {
        float v0 = acc[0][rg] + kcv0;
        float v1 = acc[1][rg] + kcv1;
        float m = fmaxf(v0, v1);
#pragma unroll
        for (int mask = 1; mask < 32; mask <<= 1) m = fmaxf(m, __shfl_xor(m, mask, 64));
        float sv = __expf(v0 - m) + __expf(v1 - m);
#pragma unroll
        for (int mask = 1; mask < 32; mask <<= 1) sv += __shfl_xor(sv, mask, 64);
        if (r32 == 0) {
            const int R = (rg & 3) + 8 * (rg >> 2) + 4 * (l >> 5);
            sM[R][cq] = m; sS[R][cq] = sv;
        }
    }
    __syncthreads();

    if (t < 32) {
        const float m0 = sM[t][0], m1 = sM[t][1], m2 = sM[t][2], m3 = sM[t][3];
        const float M = fmaxf(fmaxf(m0, m1), fmaxf(m2, m3));
        const float Sv = sS[t][0] * __expf(m0 - M) + sS[t][1] * __expf(m1 - M)
                       + sS[t][2] * __expf(m2 - M) + sS[t][3] * __expf(m3 - M);
        out[(size_t)blockIdx.x * 32 + t] = M + __logf(Sv) - thr[0];
    }
}

extern "C" void kernel_launch(void* const* d_in, const int* in_sizes, int n_in,
                              void* d_out, int out_size, void* d_ws, size_t ws_size,
                              hipStream_t stream) {
    const float* points  = (const float*)d_in[0];
    const float* centers = (const float*)d_in[1];
    const float* covs    = (const float*)d_in[2];
    const float* weights = (const float*)d_in[3];
    const float* thr     = (const float*)d_in[4];
    float* out = (float*)d_out;

    unsigned short* PsiF = (unsigned short*)d_ws;
    float* kc2 = (float*)((char*)d_ws + PSIF_BYTES);

    gmm_pre<<<KCOMP, 256, 0, stream>>>(covs, centers, weights, PsiF, kc2);
    gmm_mfma<<<NPTS / 32, 256, 0, stream>>>(points, PsiF, kc2, thr, out);
}

// Round 9
// 132.506 us; speedup vs baseline: 1.3762x; 1.3762x over previous
//
#include <hip/hip_runtime.h>
#include <math.h>

#define NPTS 131072
#define KCOMP 256
#define DIM 32
#define NREAL 560                 // 528 tight-packed quad + 32 linear
#define NCH 18                    // 32-feature chunks: 17 full + 1 half (16)
#define PSIF_BYTES 294912         // 18 chunks * 1024 granules * 16 B
#define WS_NEED (PSIF_BYTES + KCOMP * 4)

typedef __attribute__((ext_vector_type(8))) short short8;
typedef __attribute__((ext_vector_type(16))) float f32x16;

__device__ __forceinline__ unsigned short f2bf(float v) {
    unsigned u = __float_as_uint(v);
    u += 0x7fffu + ((u >> 16) & 1u);   // RNE
    return (unsigned short)(u >> 16);
}

// pack two f32 -> two bf16 (lo | hi<<16). RTN (+0x8000) + byte-perm: 3 ops.
__device__ __forceinline__ unsigned pkbf(float lo, float hi) {
#if __has_builtin(__builtin_amdgcn_perm)
    const unsigned a = __float_as_uint(hi) + 0x8000u;
    const unsigned b = __float_as_uint(lo) + 0x8000u;
    return __builtin_amdgcn_perm(a, b, 0x07060302u);
#else
    return (unsigned)f2bf(lo) | ((unsigned)f2bf(hi) << 16);
#endif
}

// async global->LDS DMA, 16 B/lane; LDS dest = wave-uniform base + lane*16.
__device__ __forceinline__ void dma16(const uint4* g, uint4* s) {
    __builtin_amdgcn_global_load_lds(
        (const __attribute__((address_space(1))) void*)g,
        (__attribute__((address_space(3))) void*)s, 16, 0, 0);
}

// counted-vmcnt barrier: newest N vmem ops (the just-issued prefetch) may
// stay in flight; everything older (previous chunk's DMA) must have landed.
// lgkmcnt(0) publishes this wave's gen ds_writes before the barrier.
template<int N>
__device__ __forceinline__ void waitbar() {
    if constexpr (N == 2)
        asm volatile("s_waitcnt vmcnt(2) lgkmcnt(0)\ns_barrier" ::: "memory");
    else if constexpr (N == 1)
        asm volatile("s_waitcnt vmcnt(1) lgkmcnt(0)\ns_barrier" ::: "memory");
    else
        asm volatile("s_waitcnt vmcnt(0) lgkmcnt(0)\ns_barrier" ::: "memory");
}

// ---- compile-time feature decode: TIGHT triangular packing ----------------
constexpr int PfxT(int d) { return 32 * d - (d * (d - 1)) / 2; }
constexpr int rowT(int p) { int d = 0; while (d < 31 && PfxT(d + 1) <= p) ++d; return d; }
constexpr int colT(int p) { return rowT(p) + (p - PfxT(rowT(p))); }

template<int P, int J>
__device__ __forceinline__ float genOne(const float (&x)[DIM]) {
    constexpr int p = P + J;
    if constexpr (p >= NREAL) {
        return 0.f;
    } else if constexpr (p >= 528) {
        return x[p - 528];
    } else {
        constexpr int d = rowT(p);
        constexpr int f = colT(p);
        static_assert(d >= 0 && d < 32 && f >= d && f < 32, "bad feature map");
        return x[d] * x[f];
    }
}

// ---------------------------------------------------------------------------
// Precompute: Psi column k scattered into frag-ordered PsiF (bf16), kc2 fp32.
// ---------------------------------------------------------------------------
__global__ __launch_bounds__(256) void gmm_pre(
    const float* __restrict__ S,
    const float* __restrict__ centers,
    const float* __restrict__ weights,
    unsigned short* __restrict__ PsiF,
    float* __restrict__ kc2)
{
    __shared__ float Sl[DIM][DIM + 1];
    __shared__ float As[DIM][DIM + 1];
    __shared__ float cl[DIM], ml[DIM];
    __shared__ float red[256];

    const int k = blockIdx.x, tid = threadIdx.x;

    for (int idx = tid; idx < DIM * DIM; idx += 256)
        Sl[idx >> 5][idx & 31] = S[(size_t)k * DIM * DIM + idx];
    if (tid < DIM) cl[tid] = centers[k * DIM + tid];
    __syncthreads();

    // A = S S^T
    for (int idx = tid; idx < DIM * DIM; idx += 256) {
        const int d = idx >> 5, f = idx & 31;
        float a = 0.f;
#pragma unroll
        for (int e = 0; e < DIM; ++e) a = fmaf(Sl[d][e], Sl[f][e], a);
        As[d][f] = a;
    }
    __syncthreads();

    if (tid < DIM) {
        float mv = 0.f;
#pragma unroll
        for (int f = 0; f < DIM; ++f) mv = fmaf(As[tid][f], cl[f], mv);
        ml[tid] = mv;
    }
    __syncthreads();

    // scatter Psi column k into frag positions (reads As diag+upper, ml).
    for (int p = tid; p < NREAL; p += 256) {
        float val;
        if (p < 528) {
            int d = 0, pr = 0;
            while (pr + (32 - d) <= p) { pr += (32 - d); ++d; }
            const int f = d + (p - pr);
            val = (f == d) ? -0.5f * As[d][d] : -As[d][f];
        } else {
            val = ml[p - 528];
        }
        const int c = p >> 6, kk = p & 63;
        const int s = kk >> 4, qq = (kk >> 3) & 1, j = kk & 7;
        const int ct = k >> 5, ll = qq * 32 + (k & 31);
        const int g = c * 2048 + (s * 8 + ct) * 64 + ll;
        PsiF[(size_t)g * 8 + j] = f2bf(val);
    }

    red[tid] = fabsf(weights[tid]);          // K == 256 == blockDim
    __syncthreads();                          // also fences As/ml reads above
    for (int off = 128; off > 0; off >>= 1) {
        if (tid < off) red[tid] += red[tid + off];
        __syncthreads();
    }
    const float wsum = red[0];

    // SPD Gaussian elimination: 1 barrier/step, logdet(A) = sum log(pivot_j).
    for (int j = 0; j < DIM - 1; ++j) {
        const float inv = 1.0f / As[j][j];
        for (int idx = tid; idx < DIM * DIM; idx += 256) {
            const int r = idx >> 5, c = idx & 31;
            if (r > j && c > j)
                As[r][c] = fmaf(-As[r][j] * inv, As[j][c], As[r][c]);
        }
        __syncthreads();
    }

    if (tid < DIM) red[tid] = __logf(As[tid][tid]);   // pivots > 0 (SPD)
    __syncthreads();
    if (tid == 0) {
        float sl = 0.f;
        for (int j = 0; j < DIM; ++j) sl += red[j];
        float cac = 0.f;
        for (int d2 = 0; d2 < DIM; ++d2) cac = fmaf(ml[d2], cl[d2], cac);
        kc2[k] = __logf(fabsf(weights[k])) - __logf(wsum + 1e-30f)
               + 0.5f * sl - 0.5f * cac;
    }
}

// ---------------------------------------------------------------------------
// Main MFMA kernel v10 = R6 dataflow (LDS A-gen, 512 thr, 128-row block,
// 3-deep counted-vmcnt B pipeline) with SWAPPED MFMA OPERANDS:
// acc = mfma(psi_granule, feat_granule) -> C[center][point-row]. Granule
// formats are A/B layout-mirrors, so the same LDS bytes serve both slots.
// Payoff is the epilogue: col = l&31 = point-row, so each lane holds 64
// CENTERS of one row -> the 256-center LSE is 64 in-reg max/exp/add + ONE
// shfl_xor(32) pair, replacing 160 LDS-pipe shuffles per wave (~31 K cy/CU,
// ~25% of the kernel's LDS traffic -- the measured near-saturated pipe).
// ---------------------------------------------------------------------------
template<int P>
__device__ __forceinline__ void genQuad(const float (&x)[DIM], float* v) {
    v[0] = genOne<P, 0>(x);
    v[1] = genOne<P, 1>(x);
    v[2] = genOne<P, 2>(x);
    v[3] = genOne<P, 3>(x);
}

// site SS (8 features) of 32-feature chunk CH -> sA buffer (CH&1)
template<int CH, int SS>
__device__ __forceinline__ void genSite(const float (&x)[DIM], uint4* base,
                                        int rbg, int r32) {
    float v[8];
    genQuad<CH * 32 + SS * 8>(x, v);
    genQuad<CH * 32 + SS * 8 + 4>(x, v + 4);
    uint4 u;
    u.x = pkbf(v[0], v[1]);
    u.y = pkbf(v[2], v[3]);
    u.z = pkbf(v[4], v[5]);
    u.w = pkbf(v[6], v[7]);
    base[(SS >> 1) * 256 + rbg * 64 + (SS & 1) * 32 + r32] = u;
}

// q = t>>7 is wave-pair-uniform: each q handles one site -> no divergence.
template<int CH>
__device__ __forceinline__ void genChunk(const float (&x)[DIM], uint4* sA4,
                                         int q, int rbg, int r32) {
    uint4* base = sA4 + (CH & 1) * 512;
    if constexpr (CH < 17) {
        if (q == 0)      genSite<CH, 0>(x, base, rbg, r32);
        else if (q == 1) genSite<CH, 1>(x, base, rbg, r32);
        else if (q == 2) genSite<CH, 2>(x, base, rbg, r32);
        else             genSite<CH, 3>(x, base, rbg, r32);
    } else {
        if (q == 0)      genSite<CH, 0>(x, base, rbg, r32);
        else if (q == 1) genSite<CH, 1>(x, base, rbg, r32);
        // q >= 2 idle: chunk 17 has only 16 features (2 sites)
    }
}

template<int C>
__device__ __forceinline__ void doChunk(const float (&x)[DIM],
    uint4* sA4, uint4* sB4, const uint4* __restrict__ PsiF4,
    f32x16 (&acc)[4],
    int l, int w, int q, int rbg, int r32, int rb, int c0)
{
    // entry (prev barrier): DMA(C) landed in sB[C%3]; DMA(C+1) in flight;
    // gen(C) complete in sA[C&1]; sB[(C+2)%3] free (body C-1 readers sealed).

    // issue DMA(C+2); its loads stay in flight across this body's barrier
    if constexpr (C + 2 < NCH) {
        constexpr int NI = (C + 2 == 17) ? 1 : 2;   // chunk 17 is 512 granules
        const uint4* src = PsiF4 + (C + 2) * 1024 + w * 64 + l;
        uint4* dst = sB4 + ((C + 2) % 3) * 1024 + w * 64 + l;
#pragma unroll
        for (int i = 0; i < NI; ++i) dma16(src + i * 512, dst + i * 512);
    }

    // gen next chunk's A into the other sA buffer (VALU; overlaps MFMA below)
    if constexpr (C + 1 < NCH) genChunk<C + 1>(x, sA4, q, rbg, r32);

    // MFMA, operands SWAPPED: M = centers (psi granule), N = point-rows
    // (feature granule). Same LDS reads as before; only the call changes.
    constexpr int NS = (C < 17) ? 2 : 1;            // K16-steps in this chunk
    const uint4* aa = sA4 + (C & 1) * 512;
    const uint4* bb = sB4 + (C % 3) * 1024;
#pragma unroll
    for (int s = 0; s < NS; ++s) {
        short8 feat = __builtin_bit_cast(short8, aa[(s * 4 + rb) * 64 + l]);
#pragma unroll
        for (int j = 0; j < 4; ++j) {
            short8 psi = __builtin_bit_cast(short8, bb[(s * 8 + c0 + j) * 64 + l]);
            acc[j] = __builtin_amdgcn_mfma_f32_32x32x16_bf16(psi, feat, acc[j], 0, 0, 0);
        }
    }

    // end barrier: certify DMA(C+1); let DMA(C+2)'s loads keep flying.
    if constexpr (C <= 14)      waitbar<2>();
    else if constexpr (C == 15) waitbar<1>();   // only chunk-17's 1 load flies
    else if constexpr (C == 16) waitbar<0>();   // drain: body 17 reads sB[2]
    // C == 17: no barrier (epilogue overlay is disjoint from body-17 reads)
}

__global__ __launch_bounds__(512, 4) void gmm_mfma(
    const float* __restrict__ points,
    const unsigned short* __restrict__ PsiF,
    const float* __restrict__ kc2,
    const float* __restrict__ thr,
    float* __restrict__ out)
{
    __shared__ uint4 sA4[1024];          // 16 KB: A double buffer (2 x 8 KB)
    __shared__ uint4 sB4[3072];          // 48 KB: B triple buffer (3 x 16 KB)
    // epilogue scratch overlaid on sA4 buffer 0 (bytes 0..2K; body-17 reads
    // sA[1] bytes 8-16K + sB[2] -- disjoint): sM 1 KB, sS 1 KB
    float (*sM)[2] = (float (*)[2])sA4;
    float (*sS)[2] = (float (*)[2])(sA4 + 64);

    const int t = threadIdx.x;
    const int w = t >> 6, l = t & 63;
    const int row = t & 127, q = t >> 7;           // gen role: one site per q
    const int rbg = row >> 5, r32 = row & 31;
    const int rb = w >> 1, c0 = (w & 1) * 4;       // wave: 32 rows x 128 centers

    const uint4* PsiF4 = (const uint4*)PsiF;

    // prologue DMA: chunk 0 -> sB[0], chunk 1 -> sB[1]
    {
        const uint4* src = PsiF4 + w * 64 + l;
        uint4* dst = sB4 + w * 64 + l;
        dma16(src,        dst);
        dma16(src +  512, dst +  512);
        dma16(src + 1024, dst + 1024);
        dma16(src + 1536, dst + 1536);
    }

    float x[DIM];
    const float4* px = (const float4*)(points + ((size_t)blockIdx.x * 128 + row) * DIM);
#pragma unroll
    for (int j2 = 0; j2 < 8; ++j2) {
        float4 v = px[j2];
        x[4 * j2 + 0] = v.x; x[4 * j2 + 1] = v.y;
        x[4 * j2 + 2] = v.z; x[4 * j2 + 3] = v.w;
    }

    f32x16 acc[4];
#pragma unroll
    for (int j = 0; j < 4; ++j)
#pragma unroll
        for (int r = 0; r < 16; ++r) acc[j][r] = 0.f;

    genChunk<0>(x, sA4, q, rbg, r32);
    __syncthreads();   // one-time full drain: chunk 0+1 DMA, x, gen(0) ready

    doChunk<0>(x, sA4, sB4, PsiF4, acc, l, w, q, rbg, r32, rb, c0);
    doChunk<1>(x, sA4, sB4, PsiF4, acc, l, w, q, rbg, r32, rb, c0);
    doChunk<2>(x, sA4, sB4, PsiF4, acc, l, w, q, rbg, r32, rb, c0);
    doChunk<3>(x, sA4, sB4, PsiF4, acc, l, w, q, rbg, r32, rb, c0);
    doChunk<4>(x, sA4, sB4, PsiF4, acc, l, w, q, rbg, r32, rb, c0);
    doChunk<5>(x, sA4, sB4, PsiF4, acc, l, w, q, rbg, r32, rb, c0);
    doChunk<6>(x, sA4, sB4, PsiF4, acc, l, w, q, rbg, r32, rb, c0);
    doChunk<7>(x, sA4, sB4, PsiF4, acc, l, w, q, rbg, r32, rb, c0);
    doChunk<8>(x, sA4, sB4, PsiF4, acc, l, w, q, rbg, r32, rb, c0);
    doChunk<9>(x, sA4, sB4, PsiF4, acc, l, w, q, rbg, r32, rb, c0);
    doChunk<10>(x, sA4, sB4, PsiF4, acc, l, w, q, rbg, r32, rb, c0);
    doChunk<11>(x, sA4, sB4, PsiF4, acc, l, w, q, rbg, r32, rb, c0);
    doChunk<12>(x, sA4, sB4, PsiF4, acc, l, w, q, rbg, r32, rb, c0);
    doChunk<13>(x, sA4, sB4, PsiF4, acc, l, w, q, rbg, r32, rb, c0);
    doChunk<14>(x, sA4, sB4, PsiF4, acc, l, w, q, rbg, r32, rb, c0);
    doChunk<15>(x, sA4, sB4, PsiF4, acc, l, w, q, rbg, r32, rb, c0);
    doChunk<16>(x, sA4, sB4, PsiF4, acc, l, w, q, rbg, r32, rb, c0);
    doChunk<17>(x, sA4, sB4, PsiF4, acc, l, w, q, rbg, r32, rb, c0);

    // ---- epilogue: lane-local LSE over this wave's 128 centers -----------
    // lane value (j, rg) = C[center][row]: row = rb*32 + (l&31),
    // center = (c0+j)*32 + (rg&3) + 8*(rg>>2) + 4*(l>>5).
    const int hi = l >> 5;
    float mloc = -INFINITY;
#pragma unroll
    for (int j = 0; j < 4; ++j) {
        const float* kp = kc2 + (c0 + j) * 32 + 4 * hi;
        const float4 q0 = *(const float4*)(kp);
        const float4 q1 = *(const float4*)(kp + 8);
        const float4 q2 = *(const float4*)(kp + 16);
        const float4 q3 = *(const float4*)(kp + 24);
#define KADD(R, QC) { float _v = acc[j][R] + (QC); acc[j][R] = _v; mloc = fmaxf(mloc, _v); }
        KADD(0, q0.x)  KADD(1, q0.y)  KADD(2, q0.z)  KADD(3, q0.w)
        KADD(4, q1.x)  KADD(5, q1.y)  KADD(6, q1.z)  KADD(7, q1.w)
        KADD(8, q2.x)  KADD(9, q2.y)  KADD(10, q2.z) KADD(11, q2.w)
        KADD(12, q3.x) KADD(13, q3.y) KADD(14, q3.z) KADD(15, q3.w)
#undef KADD
    }
    // merge the two lane-halves (same row, complementary centers)
    mloc = fmaxf(mloc, __shfl_xor(mloc, 32, 64));
    float sv = 0.f;
#pragma unroll
    for (int j = 0; j < 4; ++j)
#pragma unroll
        for (int rg = 0; rg < 16; ++rg)
            sv += __expf(acc[j][rg] - mloc);
    sv += __shfl_xor(sv, 32, 64);

    if (l < 32)
        { sM[rb * 32 + l][w & 1] = mloc; sS[rb * 32 + l][w & 1] = sv; }
    __syncthreads();

    if (t < 128) {
        const float m0 = sM[t][0], m1 = sM[t][1];
        const float M = fmaxf(m0, m1);
        const float Sv = sS[t][0] * __expf(m0 - M) + sS[t][1] * __expf(m1 - M);
        out[(size_t)blockIdx.x * 128 + t] = M + __logf(Sv) - thr[0];
    }
}

extern "C" void kernel_launch(void* const* d_in, const int* in_sizes, int n_in,
                              void* d_out, int out_size, void* d_ws, size_t ws_size,
                              hipStream_t stream) {
    const float* points  = (const float*)d_in[0];
    const float* centers = (const float*)d_in[1];
    const float* covs    = (const float*)d_in[2];
    const float* weights = (const float*)d_in[3];
    const float* thr     = (const float*)d_in[4];
    float* out = (float*)d_out;

    unsigned short* PsiF = (unsigned short*)d_ws;
    float* kc2 = (float*)((char*)d_ws + PSIF_BYTES);

    gmm_pre<<<KCOMP, 256, 0, stream>>>(covs, centers, weights, PsiF, kc2);
    gmm_mfma<<<NPTS / 128, 512, 0, stream>>>(points, PsiF, kc2, thr, out);
}

// Round 10
// 130.160 us; speedup vs baseline: 1.4010x; 1.0180x over previous
//
#include <hip/hip_runtime.h>
#include <math.h>

#define NPTS 131072
#define KCOMP 256
#define DIM 32
#define NREAL 560                 // 528 tight-packed quad + 32 linear
#define NCH 18                    // 32-feature chunks: 17 full + 1 half (16)
#define PSIF_BYTES 294912         // 18 chunks * 1024 granules * 16 B
#define WS_NEED (PSIF_BYTES + KCOMP * 4)

typedef __attribute__((ext_vector_type(8))) short short8;
typedef __attribute__((ext_vector_type(16))) float f32x16;

__device__ __forceinline__ unsigned short f2bf(float v) {
    unsigned u = __float_as_uint(v);
    u += 0x7fffu + ((u >> 16) & 1u);   // RNE
    return (unsigned short)(u >> 16);
}

// pack two f32 -> two bf16 (lo | hi<<16). RTN (+0x8000) + byte-perm: 3 ops.
__device__ __forceinline__ unsigned pkbf(float lo, float hi) {
#if __has_builtin(__builtin_amdgcn_perm)
    const unsigned a = __float_as_uint(hi) + 0x8000u;
    const unsigned b = __float_as_uint(lo) + 0x8000u;
    return __builtin_amdgcn_perm(a, b, 0x07060302u);
#else
    return (unsigned)f2bf(lo) | ((unsigned)f2bf(hi) << 16);
#endif
}

// async global->LDS DMA, 16 B/lane; LDS dest = wave-uniform base + lane*16.
__device__ __forceinline__ void dma16(const uint4* g, uint4* s) {
    __builtin_amdgcn_global_load_lds(
        (const __attribute__((address_space(1))) void*)g,
        (__attribute__((address_space(3))) void*)s, 16, 0, 0);
}

// counted-vmcnt barrier: newest N vmem ops (the just-issued prefetch) may
// stay in flight; everything older (previous chunk's DMA) must have landed.
// lgkmcnt(0) publishes this wave's gen ds_writes before the barrier.
template<int N>
__device__ __forceinline__ void waitbar() {
    if constexpr (N == 2)
        asm volatile("s_waitcnt vmcnt(2) lgkmcnt(0)\ns_barrier" ::: "memory");
    else if constexpr (N == 1)
        asm volatile("s_waitcnt vmcnt(1) lgkmcnt(0)\ns_barrier" ::: "memory");
    else
        asm volatile("s_waitcnt vmcnt(0) lgkmcnt(0)\ns_barrier" ::: "memory");
}

// ---- compile-time feature decode: TIGHT triangular packing ----------------
constexpr int PfxT(int d) { return 32 * d - (d * (d - 1)) / 2; }
constexpr int rowT(int p) { int d = 0; while (d < 31 && PfxT(d + 1) <= p) ++d; return d; }
constexpr int colT(int p) { return rowT(p) + (p - PfxT(rowT(p))); }

template<int P, int J>
__device__ __forceinline__ float genOne(const float (&x)[DIM]) {
    constexpr int p = P + J;
    if constexpr (p >= NREAL) {
        return 0.f;
    } else if constexpr (p >= 528) {
        return x[p - 528];
    } else {
        constexpr int d = rowT(p);
        constexpr int f = colT(p);
        static_assert(d >= 0 && d < 32 && f >= d && f < 32, "bad feature map");
        return x[d] * x[f];
    }
}

// ---------------------------------------------------------------------------
// Precompute: Psi column k scattered into frag-ordered PsiF (bf16), kc2 fp32.
// ---------------------------------------------------------------------------
__global__ __launch_bounds__(256) void gmm_pre(
    const float* __restrict__ S,
    const float* __restrict__ centers,
    const float* __restrict__ weights,
    unsigned short* __restrict__ PsiF,
    float* __restrict__ kc2)
{
    __shared__ float Sl[DIM][DIM + 1];
    __shared__ float As[DIM][DIM + 1];
    __shared__ float cl[DIM], ml[DIM];
    __shared__ float red[256];

    const int k = blockIdx.x, tid = threadIdx.x;

    for (int idx = tid; idx < DIM * DIM; idx += 256)
        Sl[idx >> 5][idx & 31] = S[(size_t)k * DIM * DIM + idx];
    if (tid < DIM) cl[tid] = centers[k * DIM + tid];
    __syncthreads();

    // A = S S^T
    for (int idx = tid; idx < DIM * DIM; idx += 256) {
        const int d = idx >> 5, f = idx & 31;
        float a = 0.f;
#pragma unroll
        for (int e = 0; e < DIM; ++e) a = fmaf(Sl[d][e], Sl[f][e], a);
        As[d][f] = a;
    }
    __syncthreads();

    if (tid < DIM) {
        float mv = 0.f;
#pragma unroll
        for (int f = 0; f < DIM; ++f) mv = fmaf(As[tid][f], cl[f], mv);
        ml[tid] = mv;
    }
    __syncthreads();

    // scatter Psi column k into frag positions (reads As diag+upper, ml).
    for (int p = tid; p < NREAL; p += 256) {
        float val;
        if (p < 528) {
            int d = 0, pr = 0;
            while (pr + (32 - d) <= p) { pr += (32 - d); ++d; }
            const int f = d + (p - pr);
            val = (f == d) ? -0.5f * As[d][d] : -As[d][f];
        } else {
            val = ml[p - 528];
        }
        const int c = p >> 6, kk = p & 63;
        const int s = kk >> 4, qq = (kk >> 3) & 1, j = kk & 7;
        const int ct = k >> 5, ll = qq * 32 + (k & 31);
        const int g = c * 2048 + (s * 8 + ct) * 64 + ll;
        PsiF[(size_t)g * 8 + j] = f2bf(val);
    }

    red[tid] = fabsf(weights[tid]);          // K == 256 == blockDim
    __syncthreads();                          // also fences As/ml reads above
    for (int off = 128; off > 0; off >>= 1) {
        if (tid < off) red[tid] += red[tid + off];
        __syncthreads();
    }
    const float wsum = red[0];

    // SPD Gaussian elimination: 1 barrier/step, logdet(A) = sum log(pivot_j).
    for (int j = 0; j < DIM - 1; ++j) {
        const float inv = 1.0f / As[j][j];
        for (int idx = tid; idx < DIM * DIM; idx += 256) {
            const int r = idx >> 5, c = idx & 31;
            if (r > j && c > j)
                As[r][c] = fmaf(-As[r][j] * inv, As[j][c], As[r][c]);
        }
        __syncthreads();
    }

    if (tid < DIM) red[tid] = __logf(As[tid][tid]);   // pivots > 0 (SPD)
    __syncthreads();
    if (tid == 0) {
        float sl = 0.f;
        for (int j = 0; j < DIM; ++j) sl += red[j];
        float cac = 0.f;
        for (int d2 = 0; d2 < DIM; ++d2) cac = fmaf(ml[d2], cl[d2], cac);
        kc2[k] = __logf(fabsf(weights[k])) - __logf(wsum + 1e-30f)
               + 0.5f * sl - 0.5f * cac;
    }
}

// ---------------------------------------------------------------------------
// Main MFMA kernel v11 = R9 (swapped operands, lane-local LSE, LDS A-gen,
// 3-deep counted-vmcnt B pipeline) with 2x2-GRANULE WAVE TILES:
// wave = 2 row-granules x 2 center-granules (64 rows x 64 centers), 8 waves
// cover the 4rg x 8cg grid. reads/MFMA drops 1.25 -> 1.0 (64 vs 80
// ds_read_b128 per chunk-block, -20% main-loop LDS traffic -- the measured
// dominant pipe at ~62%), with acc/occupancy UNCHANGED (4 x f32x16 = 64
// AGPR, 4 waves/SIMD). The 2x4 tile (0.75 reads/MFMA) is deliberately
// rejected: 128 AGPR halves occupancy, and R1-vs-R4 showed occupancy
// dominates read-ratio in this regime.
// ---------------------------------------------------------------------------
template<int P>
__device__ __forceinline__ void genQuad(const float (&x)[DIM], float* v) {
    v[0] = genOne<P, 0>(x);
    v[1] = genOne<P, 1>(x);
    v[2] = genOne<P, 2>(x);
    v[3] = genOne<P, 3>(x);
}

// site SS (8 features) of 32-feature chunk CH -> sA buffer (CH&1)
template<int CH, int SS>
__device__ __forceinline__ void genSite(const float (&x)[DIM], uint4* base,
                                        int rbg, int r32) {
    float v[8];
    genQuad<CH * 32 + SS * 8>(x, v);
    genQuad<CH * 32 + SS * 8 + 4>(x, v + 4);
    uint4 u;
    u.x = pkbf(v[0], v[1]);
    u.y = pkbf(v[2], v[3]);
    u.z = pkbf(v[4], v[5]);
    u.w = pkbf(v[6], v[7]);
    base[(SS >> 1) * 256 + rbg * 64 + (SS & 1) * 32 + r32] = u;
}

// q = t>>7 is wave-pair-uniform: each q handles one site -> no divergence.
template<int CH>
__device__ __forceinline__ void genChunk(const float (&x)[DIM], uint4* sA4,
                                         int q, int rbg, int r32) {
    uint4* base = sA4 + (CH & 1) * 512;
    if constexpr (CH < 17) {
        if (q == 0)      genSite<CH, 0>(x, base, rbg, r32);
        else if (q == 1) genSite<CH, 1>(x, base, rbg, r32);
        else if (q == 2) genSite<CH, 2>(x, base, rbg, r32);
        else             genSite<CH, 3>(x, base, rbg, r32);
    } else {
        if (q == 0)      genSite<CH, 0>(x, base, rbg, r32);
        else if (q == 1) genSite<CH, 1>(x, base, rbg, r32);
        // q >= 2 idle: chunk 17 has only 16 features (2 sites)
    }
}

template<int C>
__device__ __forceinline__ void doChunk(const float (&x)[DIM],
    uint4* sA4, uint4* sB4, const uint4* __restrict__ PsiF4,
    f32x16 (&acc)[2][2],
    int l, int w, int q, int rbg, int r32, int rgp, int cgp)
{
    // entry (prev barrier): DMA(C) landed in sB[C%3]; DMA(C+1) in flight;
    // gen(C) complete in sA[C&1]; sB[(C+2)%3] free (body C-1 readers sealed).

    // issue DMA(C+2); its loads stay in flight across this body's barrier
    if constexpr (C + 2 < NCH) {
        constexpr int NI = (C + 2 == 17) ? 1 : 2;   // chunk 17 is 512 granules
        const uint4* src = PsiF4 + (C + 2) * 1024 + w * 64 + l;
        uint4* dst = sB4 + ((C + 2) % 3) * 1024 + w * 64 + l;
#pragma unroll
        for (int i = 0; i < NI; ++i) dma16(src + i * 512, dst + i * 512);
    }

    // gen next chunk's A into the other sA buffer (VALU; overlaps MFMA below)
    if constexpr (C + 1 < NCH) genChunk<C + 1>(x, sA4, q, rbg, r32);

    // MFMA, swapped operands: M = centers (psi), N = point-rows (feat).
    // Wave tile 2x2 granules: feat {rgp*2, rgp*2+1}, psi {cgp*2, cgp*2+1}.
    constexpr int NS = (C < 17) ? 2 : 1;            // K16-steps in this chunk
    const uint4* aa = sA4 + (C & 1) * 512;
    const uint4* bb = sB4 + (C % 3) * 1024;
#pragma unroll
    for (int s = 0; s < NS; ++s) {
        short8 f0 = __builtin_bit_cast(short8, aa[(s * 4 + rgp * 2 + 0) * 64 + l]);
        short8 f1 = __builtin_bit_cast(short8, aa[(s * 4 + rgp * 2 + 1) * 64 + l]);
#pragma unroll
        for (int cj = 0; cj < 2; ++cj) {
            short8 psi = __builtin_bit_cast(short8, bb[(s * 8 + cgp * 2 + cj) * 64 + l]);
            acc[0][cj] = __builtin_amdgcn_mfma_f32_32x32x16_bf16(psi, f0, acc[0][cj], 0, 0, 0);
            acc[1][cj] = __builtin_amdgcn_mfma_f32_32x32x16_bf16(psi, f1, acc[1][cj], 0, 0, 0);
        }
    }

    // end barrier: certify DMA(C+1); let DMA(C+2)'s loads keep flying.
    if constexpr (C <= 14)      waitbar<2>();
    else if constexpr (C == 15) waitbar<1>();   // only chunk-17's 1 load flies
    else if constexpr (C == 16) waitbar<0>();   // drain: body 17 reads sB[2]
    // C == 17: no barrier (epilogue overlay is disjoint from body-17 reads)
}

__global__ __launch_bounds__(512, 4) void gmm_mfma(
    const float* __restrict__ points,
    const unsigned short* __restrict__ PsiF,
    const float* __restrict__ kc2,
    const float* __restrict__ thr,
    float* __restrict__ out)
{
    __shared__ uint4 sA4[1024];          // 16 KB: A double buffer (2 x 8 KB)
    __shared__ uint4 sB4[3072];          // 48 KB: B triple buffer (3 x 16 KB)
    // epilogue scratch overlaid on sA4 buffer 0 (bytes 0..4K; body-17 reads
    // sA[1] bytes 8-16K + sB[2] -- disjoint): sM 2 KB, sS 2 KB
    float (*sM)[4] = (float (*)[4])sA4;
    float (*sS)[4] = (float (*)[4])(sA4 + 128);

    const int t = threadIdx.x;
    const int w = t >> 6, l = t & 63;
    const int row = t & 127, q = t >> 7;           // gen role: one site per q
    const int rbg = row >> 5, r32 = row & 31;
    const int rgp = w >> 2, cgp = w & 3;           // wave: 64 rows x 64 centers

    const uint4* PsiF4 = (const uint4*)PsiF;

    // prologue DMA: chunk 0 -> sB[0], chunk 1 -> sB[1]
    {
        const uint4* src = PsiF4 + w * 64 + l;
        uint4* dst = sB4 + w * 64 + l;
        dma16(src,        dst);
        dma16(src +  512, dst +  512);
        dma16(src + 1024, dst + 1024);
        dma16(src + 1536, dst + 1536);
    }

    float x[DIM];
    const float4* px = (const float4*)(points + ((size_t)blockIdx.x * 128 + row) * DIM);
#pragma unroll
    for (int j2 = 0; j2 < 8; ++j2) {
        float4 v = px[j2];
        x[4 * j2 + 0] = v.x; x[4 * j2 + 1] = v.y;
        x[4 * j2 + 2] = v.z; x[4 * j2 + 3] = v.w;
    }

    f32x16 acc[2][2];
#pragma unroll
    for (int ri = 0; ri < 2; ++ri)
#pragma unroll
        for (int cj = 0; cj < 2; ++cj)
#pragma unroll
            for (int r = 0; r < 16; ++r) acc[ri][cj][r] = 0.f;

    genChunk<0>(x, sA4, q, rbg, r32);
    __syncthreads();   // one-time full drain: chunk 0+1 DMA, x, gen(0) ready

    doChunk<0>(x, sA4, sB4, PsiF4, acc, l, w, q, rbg, r32, rgp, cgp);
    doChunk<1>(x, sA4, sB4, PsiF4, acc, l, w, q, rbg, r32, rgp, cgp);
    doChunk<2>(x, sA4, sB4, PsiF4, acc, l, w, q, rbg, r32, rgp, cgp);
    doChunk<3>(x, sA4, sB4, PsiF4, acc, l, w, q, rbg, r32, rgp, cgp);
    doChunk<4>(x, sA4, sB4, PsiF4, acc, l, w, q, rbg, r32, rgp, cgp);
    doChunk<5>(x, sA4, sB4, PsiF4, acc, l, w, q, rbg, r32, rgp, cgp);
    doChunk<6>(x, sA4, sB4, PsiF4, acc, l, w, q, rbg, r32, rgp, cgp);
    doChunk<7>(x, sA4, sB4, PsiF4, acc, l, w, q, rbg, r32, rgp, cgp);
    doChunk<8>(x, sA4, sB4, PsiF4, acc, l, w, q, rbg, r32, rgp, cgp);
    doChunk<9>(x, sA4, sB4, PsiF4, acc, l, w, q, rbg, r32, rgp, cgp);
    doChunk<10>(x, sA4, sB4, PsiF4, acc, l, w, q, rbg, r32, rgp, cgp);
    doChunk<11>(x, sA4, sB4, PsiF4, acc, l, w, q, rbg, r32, rgp, cgp);
    doChunk<12>(x, sA4, sB4, PsiF4, acc, l, w, q, rbg, r32, rgp, cgp);
    doChunk<13>(x, sA4, sB4, PsiF4, acc, l, w, q, rbg, r32, rgp, cgp);
    doChunk<14>(x, sA4, sB4, PsiF4, acc, l, w, q, rbg, r32, rgp, cgp);
    doChunk<15>(x, sA4, sB4, PsiF4, acc, l, w, q, rbg, r32, rgp, cgp);
    doChunk<16>(x, sA4, sB4, PsiF4, acc, l, w, q, rbg, r32, rgp, cgp);
    doChunk<17>(x, sA4, sB4, PsiF4, acc, l, w, q, rbg, r32, rgp, cgp);

    // ---- epilogue: lane-local LSE over this wave's 2x2 granule tile ------
    // lane value (ri, cj, rg) = C[center][row]:
    //   row    = (rgp*2 + ri)*32 + (l&31)
    //   center = (cgp*2 + cj)*32 + (rg&3) + 8*(rg>>2) + 4*(l>>5)
    const int hi = l >> 5;
    float mr[2] = { -INFINITY, -INFINITY };
#pragma unroll
    for (int cj = 0; cj < 2; ++cj) {
        const float* kp = kc2 + (cgp * 2 + cj) * 32 + 4 * hi;
        const float4 q0 = *(const float4*)(kp);
        const float4 q1 = *(const float4*)(kp + 8);
        const float4 q2 = *(const float4*)(kp + 16);
        const float4 q3 = *(const float4*)(kp + 24);
#pragma unroll
        for (int ri = 0; ri < 2; ++ri) {
#define KADD(R, QC) { float _v = acc[ri][cj][R] + (QC); acc[ri][cj][R] = _v; mr[ri] = fmaxf(mr[ri], _v); }
            KADD(0, q0.x)  KADD(1, q0.y)  KADD(2, q0.z)  KADD(3, q0.w)
            KADD(4, q1.x)  KADD(5, q1.y)  KADD(6, q1.z)  KADD(7, q1.w)
            KADD(8, q2.x)  KADD(9, q2.y)  KADD(10, q2.z) KADD(11, q2.w)
            KADD(12, q3.x) KADD(13, q3.y) KADD(14, q3.z) KADD(15, q3.w)
#undef KADD
        }
    }
#pragma unroll
    for (int ri = 0; ri < 2; ++ri) {
        // merge lane-halves (same rows, complementary center offsets)
        float m = fmaxf(mr[ri], __shfl_xor(mr[ri], 32, 64));
        float sv = 0.f;
#pragma unroll
        for (int cj = 0; cj < 2; ++cj)
#pragma unroll
            for (int rg = 0; rg < 16; ++rg)
                sv += __expf(acc[ri][cj][rg] - m);
        sv += __shfl_xor(sv, 32, 64);
        if (l < 32) {
            sM[(rgp * 2 + ri) * 32 + l][cgp] = m;
            sS[(rgp * 2 + ri) * 32 + l][cgp] = sv;
        }
    }
    __syncthreads();

    if (t < 128) {
        const float m0 = sM[t][0], m1 = sM[t][1], m2 = sM[t][2], m3 = sM[t][3];
        const float M = fmaxf(fmaxf(m0, m1), fmaxf(m2, m3));
        const float Sv = sS[t][0] * __expf(m0 - M) + sS[t][1] * __expf(m1 - M)
                       + sS[t][2] * __expf(m2 - M) + sS[t][3] * __expf(m3 - M);
        out[(size_t)blockIdx.x * 128 + t] = M + __logf(Sv) - thr[0];
    }
}

extern "C" void kernel_launch(void* const* d_in, const int* in_sizes, int n_in,
                              void* d_out, int out_size, void* d_ws, size_t ws_size,
                              hipStream_t stream) {
    const float* points  = (const float*)d_in[0];
    const float* centers = (const float*)d_in[1];
    const float* covs    = (const float*)d_in[2];
    const float* weights = (const float*)d_in[3];
    const float* thr     = (const float*)d_in[4];
    float* out = (float*)d_out;

    unsigned short* PsiF = (unsigned short*)d_ws;
    float* kc2 = (float*)((char*)d_ws + PSIF_BYTES);

    gmm_pre<<<KCOMP, 256, 0, stream>>>(covs, centers, weights, PsiF, kc2);
    gmm_mfma<<<NPTS / 128, 512, 0, stream>>>(points, PsiF, kc2, thr, out);
}